// Round 6
// baseline (230.099 us; speedup 1.0000x reference)
//
#include <hip/hip_runtime.h>

// HMM trajectory forward, rank-1+diag rewrite.
// R7: LINEAR (unnormalized) chunk recurrence: P <- E1*S + E2*P, S = sum(P*EB).
// Power-of-2 renorm every CH steps (exact); chunk log telescopes to two log2s.
// R10: coop fusion = 355us (grid.sync spin). R11: CLEN=32 lost 3us (warm
// traffic). R12: CLEN=64 + triple-buffer + lengths-free staging = 218.7us.
// R13: fuse the reduce into fwd. Init-free "last block reduces": a module
// __device__ int counter is monotonic across graph replays; every block
// (incl. early-exit) atomicAdd's it; the block seeing (old+1) % (B*NC) == 0
// is the last of this iteration. Writers: slot store -> __threadfence ->
// counter add. Winner reads slots via atomicAdd(slot, 0.0f) (device-scope
// LLC reads, safe across non-coherent per-XCD L2s) in the same deterministic
// order as the old hmm_reduce, then writes out. One dispatch total.

#define CH   8     // register pipeline depth; renorm cadence (numeric bound)
#define WARM 16    // warm-up steps (direction convergence)
#define CLEN 64    // accumulated steps per chunk
#define NB   64

__device__ int g_counter = 0;   // monotonic across graph replays; never reset

template <int CTRL, int RMASK>
__device__ __forceinline__ float dpp_add(float x) {
    int yi = __builtin_amdgcn_update_dpp(
        0, __builtin_bit_cast(int, x), CTRL, RMASK, 0xf, true);
    return x + __builtin_bit_cast(float, yi);
}

// sum over 64 lanes -> wave-uniform scalar
__device__ __forceinline__ float wave_sum64(float x) {
    x = dpp_add<0x111, 0xf>(x);   // row_shr:1
    x = dpp_add<0x112, 0xf>(x);   // row_shr:2
    x = dpp_add<0x114, 0xf>(x);   // row_shr:4
    x = dpp_add<0x118, 0xf>(x);   // row_shr:8
    x = dpp_add<0x142, 0xa>(x);   // row_bcast:15 -> rows 1,3
    x = dpp_add<0x143, 0xc>(x);   // row_bcast:31 -> row 3
    return __builtin_bit_cast(float,
        __builtin_amdgcn_readlane(__builtin_bit_cast(int, x), 63));
}

__global__ __launch_bounds__(64)
void hmm_fwd(const float* __restrict__ stop,     // (B, T+1, 64, 2)
             const float* __restrict__ start,    // (B, T+1, 64)
             const float* __restrict__ act,      // (B, T+1, 64, A)
             const int*   __restrict__ actions,  // (B, T)
             const int*   __restrict__ lengths,  // (B,)
             float* __restrict__ ws,             // (B*NC) partial C2 (log2)
             float* __restrict__ out,            // scalar result
             int T, int A, int NC, int B)
{
    const int bi   = blockIdx.x;
    const int c    = blockIdx.y;
    const int lane = threadIdx.x;
    const int Tp1  = T + 1;
    const int rowA = NB * A;

    const int a  = 1 + c * CLEN;                   // first accumulated step
    const int t0 = (c == 0) ? 1 : (a - WARM);

    const float* stopB  = stop  + (size_t)bi * Tp1 * NB * 2;
    const float* startB = start + (size_t)bi * Tp1 * NB;
    const float* actB   = act   + (size_t)bi * Tp1 * NB * A;
    const int*   actsB  = actions + (size_t)bi * T;

    const int L = lengths[bi];                     // block-uniform
    const int cstar = (L >= 2) ? ((L - 2) / CLEN) : 0;  // terminal chunk

    if (c <= cstar) {
        // Stage act element-offsets (t*rowA + action[t]); clamp with T-1
        // (always in-bounds, independent of lengths; overshoot rows beyond n
        // are loaded but discarded by the i<n compute guard).
        // Single-wave block: LDS write->read needs only lgkmcnt (no barrier).
        __shared__ int offL[CLEN + WARM + CH];
        for (int i = lane; i < CLEN + WARM + CH; i += 64) {
            const int tt = min(t0 + i, T - 1);
            offL[i] = tt * rowA + actsB[tt];
        }

        const int t_end = min(L, a + CLEN);        // exclusive
        const int n     = t_end - t0;              // 0 possible (L==1, c==0)
        const int nwarm = a - t0;                  // 0 or WARM

        float p = (c == 0) ? ((lane == 0) ? 1.0f : 0.0f) : 1.0f;
        float slast   = 1.0f;   // last computed S (kept scale-consistent)
        float warmcap = 0.0f;   // log2 S^u at warm boundary (incl. shifts)
        float Eshift  = 0.0f;   // total pow2 exponent removed so far

        const float* spL = stopB  + (size_t)t0 * (NB * 2) + lane * 2;
        const float* stL = startB + (size_t)t0 * NB + lane;
        const int laneA = lane * A;

        float bB[3][CH], bO[3][CH], bS[3][CH], bC[3][CH];  // triple-buffered

#define LOADF(SL, j) do {                                                    \
    const float* sp  = spL + (size_t)(j) * (CH * NB * 2);                    \
    const float* st2 = stL + (size_t)(j) * (CH * NB);                        \
    _Pragma("unroll")                                                        \
    for (int i = 0; i < CH; ++i) {                                           \
        bC[SL][i] = actB[offL[(j) * CH + i] + laneA];                        \
        const float2 so = *(const float2*)(sp + i * (NB * 2));               \
        bB[SL][i] = so.x;                                                    \
        bO[SL][i] = so.y;                                                    \
        bS[SL][i] = st2[i * NB];                                             \
    } } while (0)

#define LOADC(SL, j) do {                                                    \
    _Pragma("unroll")                                                        \
    for (int i = 0; i < CH; ++i) {                                           \
        bC[SL][i] = actB[offL[(j) * CH + i] + laneA];                        \
        const int tt = min(t0 + (j) * CH + i, T);   /* rows 0..T valid */    \
        const float2 so = *(const float2*)(stopB + (size_t)tt * (NB * 2)     \
                                           + lane * 2);                      \
        bB[SL][i] = so.x;                                                    \
        bO[SL][i] = so.y;                                                    \
        bS[SL][i] = startB[(size_t)tt * NB + lane];                          \
    } } while (0)

#define LOAD(SL, j) do {                                                     \
    if (((j) + 1) * CH <= n) LOADF(SL, j); else LOADC(SL, j); } while (0)

#define COMPUTE(SL, j) do {                                                  \
    _Pragma("unroll")                                                        \
    for (int i = 0; i < CH; ++i) {                                           \
        if ((j) * CH + i < n) {                                              \
            const float e1 = __expf(bC[SL][i] + bS[SL][i]);                  \
            const float e2 = __expf(bC[SL][i] + bO[SL][i]);                  \
            const float eb = __expf(bB[SL][i]);                              \
            const float q  = e2 * p;             /* overlaps reduction */    \
            const float s  = wave_sum64(p * eb);                             \
            slast = s;                                                       \
            if ((j) * CH + i == nwarm - 1)                                   \
                warmcap = __log2f(s) + Eshift;                               \
            p = fmaf(e1, s, q);                                              \
        }                                                                    \
    }                                                                        \
    /* exact pow2 renorm (once per CH steps) */                              \
    {                                                                        \
        const unsigned sb = __builtin_bit_cast(unsigned, slast);             \
        const int ef = (int)(sb >> 23);          /* biased exponent */       \
        const float sc = __builtin_bit_cast(float,                           \
                             (unsigned)(254 - ef) << 23);   /* 2^-(ef-127) */\
        p *= sc;                                                             \
        slast *= sc;                                                         \
        Eshift += (float)(ef - 127);                                         \
    } } while (0)

        const int nch = (n + CH - 1) / CH;
        if (n > 0) {
            LOAD(0, 0);
            if (nch > 1) LOAD(1, 1);
            int j = 0;
            while (true) {
                if (j + 2 < nch) LOAD(2, j + 2);
                COMPUTE(0, j);
                ++j; if (j >= nch) break;
                if (j + 2 < nch) LOAD(0, j + 2);
                COMPUTE(1, j);
                ++j; if (j >= nch) break;
                if (j + 2 < nch) LOAD(1, j + 2);
                COMPUTE(2, j);
                ++j; if (j >= nch) break;
            }
        }

        float C2;
        if (c == cstar) {  // terminal: log2(sum_k P[k]*exp(beta_stop[L,k]))
            const float bl = stopB[(size_t)L * (NB * 2) + lane * 2];
            const float s  = wave_sum64(p * __expf(bl));
            C2 = __log2f(s) + Eshift - warmcap;
        } else {
            C2 = __log2f(slast) + Eshift - warmcap;
        }

        // Private slot per (b, c): written by exactly one block this launch.
        if (lane == 0)
            ws[(size_t)bi * NC + c] = C2;

#undef LOADF
#undef LOADC
#undef LOAD
#undef COMPUTE
    }

    // ---- init-free last-block-reduces -------------------------------------
    // Release: make the slot store visible at device scope, then count.
    __threadfence();
    int old = 0;
    if (lane == 0)
        old = atomicAdd(&g_counter, 1);
    old = __shfl(old, 0);

    const int total = B * NC;
    if (((old + 1) % total) == 0) {
        // Last block of this iteration: all slot stores are fenced & visible.
        // Read slots via device-scope atomics (LLC) -- immune to stale
        // per-XCD L2 lines. Same deterministic sum order as the old reducer.
        float acc = 0.0f;
        for (int b = lane; b < B; b += 64) {
            const int Lb = lengths[b];
            const int cs = (Lb >= 2) ? ((Lb - 2) / CLEN) : 0;
            float s = 0.0f;
            for (int cc = 0; cc <= cs; ++cc)
                s += atomicAdd(&ws[(size_t)b * NC + cc], 0.0f);
            acc += s;
        }
        const float tot = wave_sum64(acc);
        if (lane == 0)
            out[0] = -0.69314718055994531f * tot;
    }
}

extern "C" void kernel_launch(void* const* d_in, const int* in_sizes, int n_in,
                              void* d_out, int out_size, void* d_ws, size_t ws_size,
                              hipStream_t stream)
{
    const float* stop    = (const float*)d_in[0];
    const float* start   = (const float*)d_in[1];
    const float* act     = (const float*)d_in[2];
    const int*   actions = (const int*)d_in[3];
    const int*   lengths = (const int*)d_in[4];
    float* out = (float*)d_out;
    float* ws  = (float*)d_ws;

    const int B   = in_sizes[4];
    const int T   = in_sizes[3] / B;
    const int Tp1 = T + 1;
    const int A   = in_sizes[2] / (B * Tp1 * 64);

    int NC = (T - 1 + CLEN - 1) / CLEN;   // chunks covering t=1..T-1
    if (NC < 1) NC = 1;

    hmm_fwd<<<dim3(B, NC), dim3(64), 0, stream>>>(
        stop, start, act, actions, lengths, ws, out, T, A, NC, B);
}

// Round 7
// 216.545 us; speedup vs baseline: 1.0626x; 1.0626x over previous
//
#include <hip/hip_runtime.h>

// HMM trajectory forward, rank-1+diag rewrite.
// R7: LINEAR (unnormalized) chunk recurrence: P <- E1*S + E2*P, S = sum(P*EB).
// Power-of-2 renorm every CH steps (exact); chunk log telescopes to two log2s.
// R10: coop fusion = 355us (grid.sync spin). R11: CLEN=32 lost 3us. R12 (best,
// 218.7us): CLEN=64 + triple-buffer + lengths-free offL staging, 2 dispatches.
// R13 (230us, FAILED): fused reduce with per-block __threadfence (L2 writeback
// per block) + serial atomic-read loop in winner.
// R14: fused reduce, fence-free. Module globals g_slots[]/g_counter are
// zero-init at module load and monotonic/self-resetting across graph replays:
//   active block: atomicAdd(&g_slots[bi], C2)   (atomics go straight to LLC)
//                 s_waitcnt vmcnt(0)            (completion, no cache flush)
//                 old = atomicAdd(&g_counter,1) (all blocks, incl. early-exit)
//   winner ((old+1) % (B*NC) == 0): per-lane atomicExch(&g_slots[b], 0)
//   (reads final value AND resets for next iteration), then the same
//   deterministic wave_sum64 tree as the old hmm_reduce, lane 0 writes out.
// Ordering: every slot-add completes at LLC before its block's counter add
// issues; the winner sees the full count only after all predecessors' counter
// adds, hence all slot-adds, are LLC-visible.

#define CH   8     // register pipeline depth; renorm cadence (numeric bound)
#define WARM 16    // warm-up steps (direction convergence)
#define CLEN 64    // accumulated steps per chunk
#define NB   64
#define MAXB 256   // max supported batch (B=64 in this problem)

__device__ int   g_counter = 0;        // monotonic across iterations/replays
__device__ float g_slots[MAXB] = {};   // winner-reset to 0 every iteration

template <int CTRL, int RMASK>
__device__ __forceinline__ float dpp_add(float x) {
    int yi = __builtin_amdgcn_update_dpp(
        0, __builtin_bit_cast(int, x), CTRL, RMASK, 0xf, true);
    return x + __builtin_bit_cast(float, yi);
}

// sum over 64 lanes -> wave-uniform scalar
__device__ __forceinline__ float wave_sum64(float x) {
    x = dpp_add<0x111, 0xf>(x);   // row_shr:1
    x = dpp_add<0x112, 0xf>(x);   // row_shr:2
    x = dpp_add<0x114, 0xf>(x);   // row_shr:4
    x = dpp_add<0x118, 0xf>(x);   // row_shr:8
    x = dpp_add<0x142, 0xa>(x);   // row_bcast:15 -> rows 1,3
    x = dpp_add<0x143, 0xc>(x);   // row_bcast:31 -> row 3
    return __builtin_bit_cast(float,
        __builtin_amdgcn_readlane(__builtin_bit_cast(int, x), 63));
}

__global__ __launch_bounds__(64)
void hmm_fwd(const float* __restrict__ stop,     // (B, T+1, 64, 2)
             const float* __restrict__ start,    // (B, T+1, 64)
             const float* __restrict__ act,      // (B, T+1, 64, A)
             const int*   __restrict__ actions,  // (B, T)
             const int*   __restrict__ lengths,  // (B,)
             float* __restrict__ out,            // scalar result
             int T, int A, int NC, int B)
{
    const int bi   = blockIdx.x;
    const int c    = blockIdx.y;
    const int lane = threadIdx.x;
    const int Tp1  = T + 1;
    const int rowA = NB * A;

    const int a  = 1 + c * CLEN;                   // first accumulated step
    const int t0 = (c == 0) ? 1 : (a - WARM);

    const float* stopB  = stop  + (size_t)bi * Tp1 * NB * 2;
    const float* startB = start + (size_t)bi * Tp1 * NB;
    const float* actB   = act   + (size_t)bi * Tp1 * NB * A;
    const int*   actsB  = actions + (size_t)bi * T;

    const int L = lengths[bi];                     // block-uniform
    const int cstar = (L >= 2) ? ((L - 2) / CLEN) : 0;  // terminal chunk

    if (c <= cstar) {
        // Stage act element-offsets (t*rowA + action[t]); clamp with T-1
        // (always in-bounds, independent of lengths -> issues immediately;
        // overshoot rows beyond n are loaded but discarded by the i<n guard).
        // Single-wave block: LDS write->read needs only lgkmcnt (no barrier).
        __shared__ int offL[CLEN + WARM + CH];
        for (int i = lane; i < CLEN + WARM + CH; i += 64) {
            const int tt = min(t0 + i, T - 1);
            offL[i] = tt * rowA + actsB[tt];
        }

        const int t_end = min(L, a + CLEN);        // exclusive
        const int n     = t_end - t0;              // 0 possible (L==1, c==0)
        const int nwarm = a - t0;                  // 0 or WARM

        float p = (c == 0) ? ((lane == 0) ? 1.0f : 0.0f) : 1.0f;
        float slast   = 1.0f;   // last computed S (kept scale-consistent)
        float warmcap = 0.0f;   // log2 S^u at warm boundary (incl. shifts)
        float Eshift  = 0.0f;   // total pow2 exponent removed so far

        const float* spL = stopB  + (size_t)t0 * (NB * 2) + lane * 2;
        const float* stL = startB + (size_t)t0 * NB + lane;
        const int laneA = lane * A;

        float bB[3][CH], bO[3][CH], bS[3][CH], bC[3][CH];  // triple-buffered

#define LOADF(SL, j) do {                                                    \
    const float* sp  = spL + (size_t)(j) * (CH * NB * 2);                    \
    const float* st2 = stL + (size_t)(j) * (CH * NB);                        \
    _Pragma("unroll")                                                        \
    for (int i = 0; i < CH; ++i) {                                           \
        bC[SL][i] = actB[offL[(j) * CH + i] + laneA];                        \
        const float2 so = *(const float2*)(sp + i * (NB * 2));               \
        bB[SL][i] = so.x;                                                    \
        bO[SL][i] = so.y;                                                    \
        bS[SL][i] = st2[i * NB];                                             \
    } } while (0)

#define LOADC(SL, j) do {                                                    \
    _Pragma("unroll")                                                        \
    for (int i = 0; i < CH; ++i) {                                           \
        bC[SL][i] = actB[offL[(j) * CH + i] + laneA];                        \
        const int tt = min(t0 + (j) * CH + i, T);   /* rows 0..T valid */    \
        const float2 so = *(const float2*)(stopB + (size_t)tt * (NB * 2)     \
                                           + lane * 2);                      \
        bB[SL][i] = so.x;                                                    \
        bO[SL][i] = so.y;                                                    \
        bS[SL][i] = startB[(size_t)tt * NB + lane];                          \
    } } while (0)

#define LOAD(SL, j) do {                                                     \
    if (((j) + 1) * CH <= n) LOADF(SL, j); else LOADC(SL, j); } while (0)

#define COMPUTE(SL, j) do {                                                  \
    _Pragma("unroll")                                                        \
    for (int i = 0; i < CH; ++i) {                                           \
        if ((j) * CH + i < n) {                                              \
            const float e1 = __expf(bC[SL][i] + bS[SL][i]);                  \
            const float e2 = __expf(bC[SL][i] + bO[SL][i]);                  \
            const float eb = __expf(bB[SL][i]);                              \
            const float q  = e2 * p;             /* overlaps reduction */    \
            const float s  = wave_sum64(p * eb);                             \
            slast = s;                                                       \
            if ((j) * CH + i == nwarm - 1)                                   \
                warmcap = __log2f(s) + Eshift;                               \
            p = fmaf(e1, s, q);                                              \
        }                                                                    \
    }                                                                        \
    /* exact pow2 renorm (once per CH steps) */                              \
    {                                                                        \
        const unsigned sb = __builtin_bit_cast(unsigned, slast);             \
        const int ef = (int)(sb >> 23);          /* biased exponent */       \
        const float sc = __builtin_bit_cast(float,                           \
                             (unsigned)(254 - ef) << 23);   /* 2^-(ef-127) */\
        p *= sc;                                                             \
        slast *= sc;                                                         \
        Eshift += (float)(ef - 127);                                         \
    } } while (0)

        const int nch = (n + CH - 1) / CH;
        if (n > 0) {
            LOAD(0, 0);
            if (nch > 1) LOAD(1, 1);
            int j = 0;
            while (true) {
                if (j + 2 < nch) LOAD(2, j + 2);
                COMPUTE(0, j);
                ++j; if (j >= nch) break;
                if (j + 2 < nch) LOAD(0, j + 2);
                COMPUTE(1, j);
                ++j; if (j >= nch) break;
                if (j + 2 < nch) LOAD(1, j + 2);
                COMPUTE(2, j);
                ++j; if (j >= nch) break;
            }
        }

        float C2;
        if (c == cstar) {  // terminal: log2(sum_k P[k]*exp(beta_stop[L,k]))
            const float bl = stopB[(size_t)L * (NB * 2) + lane * 2];
            const float s  = wave_sum64(p * __expf(bl));
            C2 = __log2f(s) + Eshift - warmcap;
        } else {
            C2 = __log2f(slast) + Eshift - warmcap;
        }

        // Per-batch slot accumulation (<= NC adders, sums bounded ~2e3 ->
        // rounding noise ~1e-3). Atomics go straight to LLC: no fence needed.
        if (lane == 0)
            atomicAdd(&g_slots[bi], C2);

#undef LOADF
#undef LOADC
#undef LOAD
#undef COMPUTE
    }

    // ---- fence-free last-block-reduces ------------------------------------
    // Drain this wave's vmem (incl. the slot atomic) so the slot-add is
    // complete at LLC before the counter increment issues. No L2 writeback.
    asm volatile("s_waitcnt vmcnt(0)" ::: "memory");

    int old = 0;
    if (lane == 0)
        old = atomicAdd(&g_counter, 1);
    old = __shfl(old, 0);

    const int total = B * NC;
    if (((old + 1) % total) == 0) {
        // Last block of this iteration. All slot-adds are LLC-visible.
        // atomicExch reads the final per-batch sum AND resets the slot to 0
        // for the next iteration. One op per lane, fully parallel.
        float acc = 0.0f;
        for (int b = lane; b < B; b += 64)
            acc += atomicExch(&g_slots[b], 0.0f);
        const float tot = wave_sum64(acc);   // same tree as old hmm_reduce
        if (lane == 0)
            out[0] = -0.69314718055994531f * tot;
    }
}

extern "C" void kernel_launch(void* const* d_in, const int* in_sizes, int n_in,
                              void* d_out, int out_size, void* d_ws, size_t ws_size,
                              hipStream_t stream)
{
    const float* stop    = (const float*)d_in[0];
    const float* start   = (const float*)d_in[1];
    const float* act     = (const float*)d_in[2];
    const int*   actions = (const int*)d_in[3];
    const int*   lengths = (const int*)d_in[4];
    float* out = (float*)d_out;
    (void)d_ws; (void)ws_size;

    const int B   = in_sizes[4];
    const int T   = in_sizes[3] / B;
    const int Tp1 = T + 1;
    const int A   = in_sizes[2] / (B * Tp1 * 64);

    int NC = (T - 1 + CLEN - 1) / CLEN;   // chunks covering t=1..T-1
    if (NC < 1) NC = 1;

    hmm_fwd<<<dim3(B, NC), dim3(64), 0, stream>>>(
        stop, start, act, actions, lengths, out, T, A, NC, B);
}